// Round 11
// baseline (109.161 us; speedup 1.0000x reference)
//
#include <hip/hip_runtime.h>
#include <stdint.h>

// Problem constants (from reference):
#define T_DIM 1024
#define B_DIM 8
#define C_DIM 1024
#define H_DIM 16
#define K_SZ  7
#define P_PAD 3
#define O_DIM (H_DIM * K_SZ)   // 112
#define TB    (T_DIM * B_DIM)  // 8192 rows

typedef __attribute__((ext_vector_type(8))) short bf16x8;  // 4 VGPRs, 8 bf16
typedef __attribute__((ext_vector_type(4))) float f32x4;

union FragU { uint32_t u[4]; bf16x8 v; };

// RNE fp32->bf16 pack of two floats into one dword (lo=a, hi=b)
__device__ inline uint32_t pk_bf16(float a, float b) {
  uint32_t ua = __float_as_uint(a), ub = __float_as_uint(b);
  ua += 0x7FFFu + ((ua >> 16) & 1u);
  ub += 0x7FFFu + ((ub >> 16) & 1u);
  return (ua >> 16) | (ub & 0xFFFF0000u);
}

__device__ inline bf16x8 cvt8(f32x4 lo, f32x4 hi) {
  FragU f;
  f.u[0] = pk_bf16(lo[0], lo[1]);
  f.u[1] = pk_bf16(lo[2], lo[3]);
  f.u[2] = pk_bf16(hi[0], hi[1]);
  f.u[3] = pk_bf16(hi[2], hi[3]);
  return f.v;
}

__device__ inline bf16x8 load_bf16x8_cvt(const float* __restrict__ p) {
  f32x4 lo = *reinterpret_cast<const f32x4*>(p);
  f32x4 hi = *reinterpret_cast<const f32x4*>(p + 4);
  return cvt8(lo, hi);
}

// async global->LDS, 16B per lane: LDS dest = wave-uniform base + lane*16,
// global src = per-lane address (pre-swizzled). Counted by vmcnt.
__device__ inline void gload_lds16(const void* g, void* l) {
  __builtin_amdgcn_global_load_lds(
      (const __attribute__((address_space(1))) uint32_t*)g,
      (__attribute__((address_space(3))) uint32_t*)l, 16, 0, 0);
}

__device__ inline void sbar() {
  __builtin_amdgcn_sched_barrier(0);
  __builtin_amdgcn_s_barrier();
  __builtin_amdgcn_sched_barrier(0);
}
// orders LDS producer->consumer without draining vmcnt
__device__ inline void bar_lds() {
  __builtin_amdgcn_sched_barrier(0);
  asm volatile("s_waitcnt lgkmcnt(0)" ::: "memory");
  __builtin_amdgcn_s_barrier();
  __builtin_amdgcn_sched_barrier(0);
}
__device__ inline void vm0() {
  __builtin_amdgcn_sched_barrier(0);
  asm volatile("s_waitcnt vmcnt(0)" ::: "memory");
  __builtin_amdgcn_sched_barrier(0);
}
__device__ inline void vm4() {
  __builtin_amdgcn_sched_barrier(0);
  asm volatile("s_waitcnt vmcnt(4)" ::: "memory");
  __builtin_amdgcn_sched_barrier(0);
}

// Kernel 0: build fragment-native bf16 W.
// Wf[((ks*7)+nf)*64 + lane] (16B) = W[nf*16+(lane&15)][ks*32+(lane>>4)*8 .. +7]
__global__ __launch_bounds__(256) void prep_wfrag_kernel(
    const float* __restrict__ Wl, uint16_t* __restrict__ Wf) {
  const int t  = blockIdx.x * 256 + threadIdx.x;  // 0..14335
  const int f  = t >> 6;
  const int l  = t & 63;
  const int ks = f / 7;
  const int nf = f - ks * 7;
  const int row = nf * 16 + (l & 15);
  const int kb  = ks * 32 + (l >> 4) * 8;
  bf16x8 v = load_bf16x8_cvt(Wl + (size_t)row * C_DIM + kb);
  *reinterpret_cast<bf16x8*>(Wf + (size_t)t * 8) = v;   // coalesced 16B/lane
}

// DIAGNOSTIC build of the round-10 fused kernel: executes the ENTIRE body
// TWICE (pass 2 recomputes and rewrites identical output). Purpose: push
// dur_us above the harness's ~40us fill dispatches so this kernel finally
// appears in the rocprof top-5 and we get MfmaUtil/VALUBusy/FETCH/WRITE/
// LDS-conflict/Occupancy for the exact structure iterated since round 5.
// Numerics identical (absmax must stay 0.015625).
template <bool PREPPED>
__global__ __launch_bounds__(1024) void fused_dma_kernel(
    const float* __restrict__ x, const float* __restrict__ Wl,
    const uint16_t* __restrict__ Wf, const float* __restrict__ bl,
    const float* __restrict__ cb, float* __restrict__ out) {
  __shared__ float ring[32 * 1024];     // 128KB: 32 fp32 rows, swizzled
  __shared__ float part[2][16][116];    // 14.5KB: per-K-half logits
  __shared__ float wsm[16][17][8];      // 8.7KB: softmax weights

  const int tid  = threadIdx.x;
  const int wv   = tid >> 6;            // 0..15
  const int lane = tid & 63;
  const int l15  = lane & 15;
  const int oct  = lane >> 4;

  // XCD swizzle: xcd owns 4 contiguous 32-row window-pairs for every b.
  const int bid = blockIdx.x;           // 0..255
  const int xcd = bid & 7;
  const int r8  = bid >> 3;             // 0..31
  const int b   = r8 >> 2;              // 0..7
  const int t0  = (xcd * 4 + (r8 & 3)) * 32;

  // stage logical row (t0-3+ridx) -> ring slot (logical&31), 4 DMA chunks
  auto stage_dma = [&](int ridx) {
    const int tlog = t0 - 3 + ridx;
    const int g    = min(max(tlog, 0), T_DIM - 1);
    const int slot = tlog & 31;
    const int key  = (tlog & 7) << 4;
    const char* __restrict__ rowp =
        (const char*)(x + ((size_t)(g * B_DIM + b)) * C_DIM);
    char* ldsrow = (char*)ring + slot * 4096;
#pragma unroll
    for (int q = 0; q < 4; ++q) {
      gload_lds16(rowp + (((q * 1024) + lane * 16) ^ key), ldsrow + q * 1024);
    }
  };

  auto mfma_phase = [&](int wbase) {
    if (wv < 14) {
      const int kh = (wv >= 7) ? 1 : 0;
      const int nf = wv - kh * 7;
      const int tA = wbase + l15;
      const char* rowb = (const char*)ring + (tA & 31) * 4096;
      const int key = (tA & 7) << 4;
      f32x4 acc0 = (f32x4)(0.f), acc1 = (f32x4)(0.f);
#pragma unroll
      for (int s = 0; s < 16; ++s) {
        const int ksg   = kh * 16 + s;
        const int inrow = ksg * 128 + oct * 32;
        f32x4 lo = *reinterpret_cast<const f32x4*>(rowb + (inrow ^ key));
        f32x4 hi = *reinterpret_cast<const f32x4*>(rowb + ((inrow + 16) ^ key));
        bf16x8 a = cvt8(lo, hi);
        bf16x8 bf;
        if (PREPPED)
          bf = *reinterpret_cast<const bf16x8*>(
              Wf + ((size_t)((ksg * 7 + nf) * 64) + lane) * 8);
        else
          bf = load_bf16x8_cvt(Wl + (size_t)(nf * 16 + l15) * C_DIM + ksg * 32 + oct * 8);
        if (s < 8) acc0 = __builtin_amdgcn_mfma_f32_16x16x32_bf16(a, bf, acc0, 0, 0, 0);
        else       acc1 = __builtin_amdgcn_mfma_f32_16x16x32_bf16(a, bf, acc1, 0, 0, 0);
      }
      // D layout: col = lane&15 (W row), row = (lane>>4)*4 + reg (x row)
#pragma unroll
      for (int rr = 0; rr < 4; ++rr)
        part[kh][oct * 4 + rr][nf * 16 + l15] = acc0[rr] + acc1[rr];
    }
  };

  auto softmax_phase = [&]() {
    if (tid < 256) {
      const int row = tid >> 4;
      const int h   = tid & 15;
      float lg[7];
      float m = -1e30f;
#pragma unroll
      for (int j = 0; j < 7; ++j) {
        const int c = h * 7 + j;
        float s_ = part[0][row][c] + part[1][row][c] + bl[c];
        lg[j] = s_;
        m = fmaxf(m, s_);
      }
      float s = 0.f;
#pragma unroll
      for (int j = 0; j < 7; ++j) { lg[j] = __expf(lg[j] - m); s += lg[j]; }
      const float inv = 1.0f / s;
#pragma unroll
      for (int j = 0; j < 7; ++j) wsm[row][h][j] = lg[j] * inv;
    }
  };

  auto conv_phase = [&](int wbase) {
    const int row  = wv;               // one wave per output row
    const int gout = wbase + row;
    const char* tbase[7];
    int tkey[7];
    float okf[7];
#pragma unroll
    for (int j = 0; j < 7; ++j) {
      const int tp = gout + j - P_PAD;
      okf[j] = (tp >= 0 && tp < T_DIM) ? 1.f : 0.f;
      const int g = min(max(tp, 0), T_DIM - 1);
      tbase[j] = (const char*)ring + (g & 31) * 4096;
      tkey[j]  = (g & 7) << 4;
    }
    float* __restrict__ obase = out + ((size_t)(gout * B_DIM + b)) * C_DIM;
#pragma unroll
    for (int k = 0; k < 4; ++k) {
      const int inrow = k * 1024 + lane * 16;   // thread: 4 ch (float4)
      const int ch    = k * 256 + lane * 4;
      const int head  = k * 4 + oct;
      float4 w0 = *reinterpret_cast<const float4*>(&wsm[row][head][0]);
      float4 w1 = *reinterpret_cast<const float4*>(&wsm[row][head][4]);
      const float wj[7] = {w0.x * okf[0], w0.y * okf[1], w0.z * okf[2],
                           w0.w * okf[3], w1.x * okf[4], w1.y * okf[5],
                           w1.z * okf[6]};
      f32x4 a = *reinterpret_cast<const f32x4*>(cb + ch);
#pragma unroll
      for (int j = 0; j < 7; ++j) {
        f32x4 d = *reinterpret_cast<const f32x4*>(tbase[j] + (inrow ^ tkey[j]));
        a += wj[j] * d;
      }
      __builtin_nontemporal_store(a, reinterpret_cast<f32x4*>(obase + ch));
    }
  };

#pragma unroll 1
  for (int pass = 0; pass < 2; ++pass) {
    // ---- issue prologue DMA: logical rows idx 0..21 (t0-3 .. t0+18) ----
    for (int r = wv; r < 22; r += 16) stage_dma(r);   // wv<6: 2 rows; else 1
    // ---- issue prefetch A: rows idx 22..31 -> slots 19..28 (disjoint W0) ----
    if (wv >= 6) stage_dma(16 + wv);
    // drain own prologue, keep prefA in flight
    if (wv < 6) vm0(); else vm4();
    sbar();

    // ---- window 0 ----
    mfma_phase(t0);          // slots 0..15
    bar_lds();
    softmax_phase();
    bar_lds();
    conv_phase(t0);          // slots {29,30,31, 0..18}
    bar_lds();               // conv-W0 LDS reads retired

    // ---- prefetch B: rows idx 32..37 -> slots {29,30,31,0,1,2} (dead) ----
    if (wv < 6) { stage_dma(32 + wv); vm0(); }
    sbar();                  // prefB in LDS; mfma W1 needs slots 16..31

    // ---- window 1 ----
    mfma_phase(t0 + 16);     // slots 16..31
    bar_lds();
    softmax_phase();
    bar_lds();
    conv_phase(t0 + 16);     // slots {13..31, 0,1,2}
    bar_lds();               // pass-2 DMA must not overwrite live LDS reads
  }
}

extern "C" void kernel_launch(void* const* d_in, const int* in_sizes, int n_in,
                              void* d_out, int out_size, void* d_ws, size_t ws_size,
                              hipStream_t stream) {
  const float* x  = (const float*)d_in[0];   // (T,B,C)
  const float* Wl = (const float*)d_in[1];   // (H*K, C)
  const float* bl = (const float*)d_in[2];   // (H*K,)
  const float* cb = (const float*)d_in[3];   // (C,)
  float* out = (float*)d_out;                // (T,B,C)

  const bool prepped = ws_size >= 262144;    // 224KB frag-W, padded

  if (prepped) {
    uint16_t* wf = (uint16_t*)d_ws;
    prep_wfrag_kernel<<<(32 * 7 * 64) / 256, 256, 0, stream>>>(Wl, wf);
    fused_dma_kernel<true><<<256, 1024, 0, stream>>>(x, Wl, wf, bl, cb, out);
  } else {
    fused_dma_kernel<false><<<256, 1024, 0, stream>>>(x, Wl, nullptr, bl, cb, out);
  }
}

// Round 12
// 30.503 us; speedup vs baseline: 3.5787x; 3.5787x over previous
//
#include <hip/hip_runtime.h>
#include <stdint.h>

// Problem constants (from reference):
#define T_DIM 1024
#define B_DIM 8
#define C_DIM 1024
#define H_DIM 16
#define K_SZ  7
#define P_PAD 3
#define O_DIM (H_DIM * K_SZ)   // 112
#define TB    (T_DIM * B_DIM)  // 8192 rows

// LDS ring geometry: row stride padded +32B -> bank rotation 8/slot.
// 4128/4 = 1032 == 8 (mod 32): consecutive slots rotate bank groups, so
// MFMA A-reads (16 consecutive rows) and conv tap reads hit the uniform
// 8-access/bank floor for ds_read_b128 with NO swizzle. DMA source linear.
#define RSTRIDE 4128

typedef __attribute__((ext_vector_type(8))) short bf16x8;  // 4 VGPRs, 8 bf16
typedef __attribute__((ext_vector_type(4))) float f32x4;

union FragU { uint32_t u[4]; bf16x8 v; };

// RNE fp32->bf16 pack of two floats into one dword (lo=a, hi=b)
__device__ inline uint32_t pk_bf16(float a, float b) {
  uint32_t ua = __float_as_uint(a), ub = __float_as_uint(b);
  ua += 0x7FFFu + ((ua >> 16) & 1u);
  ub += 0x7FFFu + ((ub >> 16) & 1u);
  return (ua >> 16) | (ub & 0xFFFF0000u);
}

__device__ inline bf16x8 cvt8(f32x4 lo, f32x4 hi) {
  FragU f;
  f.u[0] = pk_bf16(lo[0], lo[1]);
  f.u[1] = pk_bf16(lo[2], lo[3]);
  f.u[2] = pk_bf16(hi[0], hi[1]);
  f.u[3] = pk_bf16(hi[2], hi[3]);
  return f.v;
}

__device__ inline bf16x8 load_bf16x8_cvt(const float* __restrict__ p) {
  f32x4 lo = *reinterpret_cast<const f32x4*>(p);
  f32x4 hi = *reinterpret_cast<const f32x4*>(p + 4);
  return cvt8(lo, hi);
}

// async global->LDS, 16B per lane: LDS dest = wave-uniform base + lane*16,
// global src per-lane LINEAR (lane*16) -> full cross-lane request merging.
__device__ inline void gload_lds16(const void* g, void* l) {
  __builtin_amdgcn_global_load_lds(
      (const __attribute__((address_space(1))) uint32_t*)g,
      (__attribute__((address_space(3))) uint32_t*)l, 16, 0, 0);
}

__device__ inline void sbar() {
  __builtin_amdgcn_sched_barrier(0);
  __builtin_amdgcn_s_barrier();
  __builtin_amdgcn_sched_barrier(0);
}
// orders LDS producer->consumer without draining vmcnt
__device__ inline void bar_lds() {
  __builtin_amdgcn_sched_barrier(0);
  asm volatile("s_waitcnt lgkmcnt(0)" ::: "memory");
  __builtin_amdgcn_s_barrier();
  __builtin_amdgcn_sched_barrier(0);
}
__device__ inline void vm0() {
  __builtin_amdgcn_sched_barrier(0);
  asm volatile("s_waitcnt vmcnt(0)" ::: "memory");
  __builtin_amdgcn_sched_barrier(0);
}
__device__ inline void vm4() {
  __builtin_amdgcn_sched_barrier(0);
  asm volatile("s_waitcnt vmcnt(4)" ::: "memory");
  __builtin_amdgcn_sched_barrier(0);
}

// Kernel 0: build fragment-native bf16 W.
// Wf[((ks*7)+nf)*64 + lane] (16B) = W[nf*16+(lane&15)][ks*32+(lane>>4)*8 .. +7]
__global__ __launch_bounds__(256) void prep_wfrag_kernel(
    const float* __restrict__ Wl, uint16_t* __restrict__ Wf) {
  const int t  = blockIdx.x * 256 + threadIdx.x;  // 0..14335
  const int f  = t >> 6;
  const int l  = t & 63;
  const int ks = f / 7;
  const int nf = f - ks * 7;
  const int row = nf * 16 + (l & 15);
  const int kb  = ks * 32 + (l >> 4) * 8;
  bf16x8 v = load_bf16x8_cvt(Wl + (size_t)row * C_DIM + kb);
  *reinterpret_cast<bf16x8*>(Wf + (size_t)t * 8) = v;   // coalesced 16B/lane
}

// Fused kernel (round-10 structure, de-amplified):
//  - fp32 ring staged by global_load_lds with LINEAR per-lane source
//  - padded row stride (no swizzle) -> conflict-free LDS at the b128 floor
//  - plain coalesced stores (no nontemporal)
template <bool PREPPED>
__global__ __launch_bounds__(1024) void fused_dma_kernel(
    const float* __restrict__ x, const float* __restrict__ Wl,
    const uint16_t* __restrict__ Wf, const float* __restrict__ bl,
    const float* __restrict__ cb, float* __restrict__ out) {
  __shared__ char  ring[32 * RSTRIDE];  // 129KB: 32 fp32 rows, padded stride
  __shared__ float part[2][16][116];    // 14.5KB: per-K-half logits
  __shared__ float wsm[16][17][8];      // 8.7KB: softmax weights

  const int tid  = threadIdx.x;
  const int wv   = tid >> 6;            // 0..15
  const int lane = tid & 63;
  const int l15  = lane & 15;
  const int oct  = lane >> 4;

  // XCD swizzle: xcd owns 4 contiguous 32-row window-pairs for every b.
  const int bid = blockIdx.x;           // 0..255
  const int xcd = bid & 7;
  const int r8  = bid >> 3;             // 0..31
  const int b   = r8 >> 2;              // 0..7
  const int t0  = (xcd * 4 + (r8 & 3)) * 32;

  // stage logical row (t0-3+ridx) -> ring slot (logical&31), 4 DMA chunks,
  // source linear per lane.
  auto stage_dma = [&](int ridx) {
    const int tlog = t0 - 3 + ridx;
    const int g    = min(max(tlog, 0), T_DIM - 1);
    const int slot = tlog & 31;
    const char* __restrict__ rowp =
        (const char*)(x + ((size_t)(g * B_DIM + b)) * C_DIM);
    char* ldsrow = ring + slot * RSTRIDE;
#pragma unroll
    for (int q = 0; q < 4; ++q) {
      gload_lds16(rowp + q * 1024 + lane * 16, ldsrow + q * 1024);
    }
  };

  auto mfma_phase = [&](int wbase) {
    if (wv < 14) {
      const int kh = (wv >= 7) ? 1 : 0;
      const int nf = wv - kh * 7;
      const int tA = wbase + l15;
      const char* rowb = ring + (tA & 31) * RSTRIDE;
      f32x4 acc0 = (f32x4)(0.f), acc1 = (f32x4)(0.f);
#pragma unroll
      for (int s = 0; s < 16; ++s) {
        const int ksg   = kh * 16 + s;
        const int inrow = ksg * 128 + oct * 32;
        f32x4 lo = *reinterpret_cast<const f32x4*>(rowb + inrow);
        f32x4 hi = *reinterpret_cast<const f32x4*>(rowb + inrow + 16);
        bf16x8 a = cvt8(lo, hi);
        bf16x8 bf;
        if (PREPPED)
          bf = *reinterpret_cast<const bf16x8*>(
              Wf + ((size_t)((ksg * 7 + nf) * 64) + lane) * 8);
        else
          bf = load_bf16x8_cvt(Wl + (size_t)(nf * 16 + l15) * C_DIM + ksg * 32 + oct * 8);
        if (s < 8) acc0 = __builtin_amdgcn_mfma_f32_16x16x32_bf16(a, bf, acc0, 0, 0, 0);
        else       acc1 = __builtin_amdgcn_mfma_f32_16x16x32_bf16(a, bf, acc1, 0, 0, 0);
      }
      // D layout: col = lane&15 (W row), row = (lane>>4)*4 + reg (x row)
#pragma unroll
      for (int rr = 0; rr < 4; ++rr)
        part[kh][oct * 4 + rr][nf * 16 + l15] = acc0[rr] + acc1[rr];
    }
  };

  auto softmax_phase = [&]() {
    if (tid < 256) {
      const int row = tid >> 4;
      const int h   = tid & 15;
      float lg[7];
      float m = -1e30f;
#pragma unroll
      for (int j = 0; j < 7; ++j) {
        const int c = h * 7 + j;
        float s_ = part[0][row][c] + part[1][row][c] + bl[c];
        lg[j] = s_;
        m = fmaxf(m, s_);
      }
      float s = 0.f;
#pragma unroll
      for (int j = 0; j < 7; ++j) { lg[j] = __expf(lg[j] - m); s += lg[j]; }
      const float inv = 1.0f / s;
#pragma unroll
      for (int j = 0; j < 7; ++j) wsm[row][h][j] = lg[j] * inv;
    }
  };

  auto conv_phase = [&](int wbase) {
    const int row  = wv;               // one wave per output row
    const int gout = wbase + row;
    const char* tbase[7];
    float okf[7];
#pragma unroll
    for (int j = 0; j < 7; ++j) {
      const int tp = gout + j - P_PAD;
      okf[j] = (tp >= 0 && tp < T_DIM) ? 1.f : 0.f;
      const int g = min(max(tp, 0), T_DIM - 1);
      tbase[j] = ring + (g & 31) * RSTRIDE;
    }
    float* __restrict__ obase = out + ((size_t)(gout * B_DIM + b)) * C_DIM;
#pragma unroll
    for (int k = 0; k < 4; ++k) {
      const int inrow = k * 1024 + lane * 16;   // thread: 4 ch (float4)
      const int ch    = k * 256 + lane * 4;
      const int head  = k * 4 + oct;
      float4 w0 = *reinterpret_cast<const float4*>(&wsm[row][head][0]);
      float4 w1 = *reinterpret_cast<const float4*>(&wsm[row][head][4]);
      const float wj[7] = {w0.x * okf[0], w0.y * okf[1], w0.z * okf[2],
                           w0.w * okf[3], w1.x * okf[4], w1.y * okf[5],
                           w1.z * okf[6]};
      f32x4 a = *reinterpret_cast<const f32x4*>(cb + ch);
#pragma unroll
      for (int j = 0; j < 7; ++j) {
        f32x4 d = *reinterpret_cast<const f32x4*>(tbase[j] + inrow);
        a += wj[j] * d;
      }
      *reinterpret_cast<f32x4*>(obase + ch) = a;   // plain coalesced store
    }
  };

  // ---- issue prologue DMA: logical rows idx 0..21 (t0-3 .. t0+18) ----
  for (int r = wv; r < 22; r += 16) stage_dma(r);   // wv<6: 2 rows; else 1
  // ---- issue prefetch A: rows idx 22..31 -> slots 19..28 (disjoint W0) ----
  if (wv >= 6) stage_dma(16 + wv);
  // drain own prologue, keep prefA in flight
  if (wv < 6) vm0(); else vm4();
  sbar();

  // ---- window 0 ----
  mfma_phase(t0);          // slots 0..15 (+ Wf loads force prefA drain by end)
  bar_lds();
  softmax_phase();
  bar_lds();
  conv_phase(t0);          // slots {29,30,31, 0..18}
  bar_lds();               // conv-W0 LDS reads retired

  // ---- prefetch B: rows idx 32..37 -> slots {29,30,31,0,1,2} (now dead) ----
  if (wv < 6) { stage_dma(32 + wv); vm0(); }
  sbar();                  // prefB in LDS; mfma W1 needs slots 16..31

  // ---- window 1 ----
  mfma_phase(t0 + 16);     // slots 16..31
  bar_lds();
  softmax_phase();
  bar_lds();
  conv_phase(t0 + 16);     // slots {13..31, 0,1,2}
}

extern "C" void kernel_launch(void* const* d_in, const int* in_sizes, int n_in,
                              void* d_out, int out_size, void* d_ws, size_t ws_size,
                              hipStream_t stream) {
  const float* x  = (const float*)d_in[0];   // (T,B,C)
  const float* Wl = (const float*)d_in[1];   // (H*K, C)
  const float* bl = (const float*)d_in[2];   // (H*K,)
  const float* cb = (const float*)d_in[3];   // (C,)
  float* out = (float*)d_out;                // (T,B,C)

  const bool prepped = ws_size >= 262144;    // 224KB frag-W, padded

  if (prepped) {
    uint16_t* wf = (uint16_t*)d_ws;
    prep_wfrag_kernel<<<(32 * 7 * 64) / 256, 256, 0, stream>>>(Wl, wf);
    fused_dma_kernel<true><<<256, 1024, 0, stream>>>(x, Wl, wf, bl, cb, out);
  } else {
    fused_dma_kernel<false><<<256, 1024, 0, stream>>>(x, Wl, nullptr, bl, cb, out);
  }
}